// Round 1
// baseline (731.968 us; speedup 1.0000x reference)
//
#include <hip/hip_runtime.h>
#include <hip/hip_bf16.h>

typedef __attribute__((ext_vector_type(8))) __bf16 bf16x8;
typedef __attribute__((ext_vector_type(4))) float floatx4;

constexpr int N_TOK = 4096;   // B*T
constexpr int DDIM  = 1024;
constexpr int FDIM  = 4096;
constexpr int NEXP  = 8;
constexpr int NSLOT = 2 * N_TOK; // 8192 assignments (top-2)

static __device__ __forceinline__ unsigned short f2bf(float f) {
    union { __hip_bfloat16 h; unsigned short u; } v;
    v.h = __float2bfloat16(f);
    return v.u;
}

// ---------------- zero output + counts ----------------
__global__ void zero_kernel(float* __restrict__ out, int* __restrict__ counts) {
    size_t i = ((size_t)blockIdx.x * 256 + threadIdx.x) * 4;
    *(float4*)(out + i) = make_float4(0.f, 0.f, 0.f, 0.f);
    if (blockIdx.x == 0 && threadIdx.x < NEXP) counts[threadIdx.x] = 0;
}

// ---------------- generic fp32 -> bf16 cast ----------------
__global__ void castN_kernel(const float* __restrict__ src, unsigned short* __restrict__ dst, int n4) {
    int i = blockIdx.x * 256 + threadIdx.x;
    if (i >= n4) return;
    float4 v = *(const float4*)(src + (size_t)i * 4);
    ushort4 o;
    o.x = f2bf(v.x); o.y = f2bf(v.y); o.z = f2bf(v.z); o.w = f2bf(v.w);
    *(ushort4*)(dst + (size_t)i * 4) = o;
}

// ---------------- router: logits -> top2 -> weights ----------------
__global__ void router_kernel(const float* __restrict__ x, const float* __restrict__ Wr,
                              int* __restrict__ te, float* __restrict__ tw,
                              int* __restrict__ counts) {
    __shared__ float wr[NEXP * DDIM]; // 32 KB
    const int tid = threadIdx.x;
    for (int i = tid; i < NEXP * DDIM; i += 256) wr[i] = Wr[i];
    __syncthreads();
    const int wave = tid >> 6, lane = tid & 63;
    const int t = blockIdx.x * 4 + wave;

    float xr[16];
    const float* xp = x + (size_t)t * DDIM;
    #pragma unroll
    for (int i = 0; i < 16; i++) xr[i] = xp[lane + 64 * i];

    float logit[NEXP];
    #pragma unroll
    for (int e = 0; e < NEXP; e++) {
        float s = 0.f;
        #pragma unroll
        for (int i = 0; i < 16; i++) s += xr[i] * wr[e * DDIM + lane + 64 * i];
        #pragma unroll
        for (int off = 32; off > 0; off >>= 1) s += __shfl_xor(s, off, 64);
        logit[e] = s;
    }
    if (lane == 0) {
        int i0 = 0; float l0 = logit[0];
        #pragma unroll
        for (int e = 1; e < NEXP; e++) if (logit[e] > l0) { l0 = logit[e]; i0 = e; }
        int i1 = -1; float l1 = -3.0e38f;
        #pragma unroll
        for (int e = 0; e < NEXP; e++) if (e != i0 && logit[e] > l1) { l1 = logit[e]; i1 = e; }
        // softmax over top-2 logits == renormalized top-2 of full softmax
        float p1 = __expf(0.f) * expf(l1 - l0);
        float w0 = 1.f / (1.f + p1);
        float w1 = p1 * w0;
        te[t * 2] = i0; te[t * 2 + 1] = i1;
        tw[t * 2] = w0; tw[t * 2 + 1] = w1;
        atomicAdd(&counts[i0], 1);
        atomicAdd(&counts[i1], 1);
    }
}

// ---------------- prefix sum over 8 counts ----------------
__global__ void scan_kernel(const int* __restrict__ counts, int* __restrict__ offsets,
                            int* __restrict__ cursors) {
    if (threadIdx.x == 0) {
        int acc = 0;
        for (int e = 0; e < NEXP; e++) { offsets[e] = acc; acc += counts[e]; }
        offsets[NEXP] = acc;
    }
    if (threadIdx.x < NEXP) cursors[threadIdx.x] = 0;
}

// ---------------- scatter tokens into expert buckets ----------------
__global__ void scatter_kernel(const int* __restrict__ te, const float* __restrict__ tw,
                               const int* __restrict__ offsets, int* __restrict__ cursors,
                               int* __restrict__ rowid, float* __restrict__ gate) {
    int t = blockIdx.x * 256 + threadIdx.x;
    if (t >= N_TOK) return;
    #pragma unroll
    for (int k = 0; k < 2; k++) {
        int e = te[t * 2 + k];
        int pos = atomicAdd(&cursors[e], 1);
        int slot = offsets[e] + pos;
        rowid[slot] = t;
        gate[slot] = tw[t * 2 + k];
    }
}

// ---------------- grouped GEMM (up: gelu->H bf16, down: gate*atomicAdd->out) ----------------
template <int K, bool UP, bool BF16W>
__global__ __launch_bounds__(256)
void ffn_gemm(const unsigned short* __restrict__ A,   // xb (UP) or H (DOWN), bf16 bits
              const float* __restrict__ Wf,           // fp32 weights
              const unsigned short* __restrict__ Wb,  // bf16 weights (if BF16W)
              unsigned short* __restrict__ Hout,
              float* __restrict__ out,
              const int* __restrict__ rowid,
              const float* __restrict__ gate,
              const int* __restrict__ offsets) {
    constexpr int BM = 128, BN = 128, BK = 32, LDT = 40; // LDT pad: 40 ushorts/row
    constexpr int NOUT = UP ? FDIM : DDIM;

    const int e = blockIdx.z;
    const int seg = offsets[e];
    const int cnt = offsets[e + 1] - seg;
    const int m0 = blockIdx.y * BM;
    if (m0 >= cnt) return;
    const int n0 = blockIdx.x * BN;

    __shared__ __align__(16) unsigned short As[BM * LDT];
    __shared__ __align__(16) unsigned short Bs[BN * LDT];

    const int tid = threadIdx.x;
    const int lane = tid & 63;
    const int wave = tid >> 6;
    const int wm = (wave >> 1) * 64;
    const int wn = (wave & 1) * 64;
    const int frow = lane & 15;
    const int quad = lane >> 4;

    floatx4 acc[4][4];
    #pragma unroll
    for (int i = 0; i < 4; i++)
        #pragma unroll
        for (int j = 0; j < 4; j++)
            acc[i][j] = (floatx4){0.f, 0.f, 0.f, 0.f};

    // staging coords: each thread loads 16 A elems + 16 B elems per K-step
    const int ar = tid >> 1;           // row 0..127
    const int ah = (tid & 1) * 16;     // k sub-offset

    int slotA = seg + m0 + ar;
    if (slotA > NSLOT - 1) slotA = NSLOT - 1;           // clamp: stay in valid memory
    const unsigned short* aptr;
    if (UP) aptr = A + (size_t)rowid[slotA] * DDIM + ah; // gathered token row
    else    aptr = A + (size_t)slotA * FDIM + ah;        // H row
    unsigned short* asdst = &As[ar * LDT + ah];
    unsigned short* bsdst = &Bs[ar * LDT + ah];
    const float* bptrf = Wf + ((size_t)e * NOUT + n0 + ar) * K + ah;
    const unsigned short* bptrb = Wb + ((size_t)e * NOUT + n0 + ar) * K + ah;

    for (int k0 = 0; k0 < K; k0 += BK) {
        uint4 a0 = *(const uint4*)(aptr);
        uint4 a1 = *(const uint4*)(aptr + 8);
        uint4 bu0, bu1;
        if (BF16W) {
            bu0 = *(const uint4*)(bptrb);
            bu1 = *(const uint4*)(bptrb + 8);
        } else {
            float4 b0 = *(const float4*)(bptrf);
            float4 b1 = *(const float4*)(bptrf + 4);
            float4 b2 = *(const float4*)(bptrf + 8);
            float4 b3 = *(const float4*)(bptrf + 12);
            union { unsigned short u[16]; uint4 q[2]; } bb;
            bb.u[0] = f2bf(b0.x); bb.u[1] = f2bf(b0.y); bb.u[2]  = f2bf(b0.z); bb.u[3]  = f2bf(b0.w);
            bb.u[4] = f2bf(b1.x); bb.u[5] = f2bf(b1.y); bb.u[6]  = f2bf(b1.z); bb.u[7]  = f2bf(b1.w);
            bb.u[8] = f2bf(b2.x); bb.u[9] = f2bf(b2.y); bb.u[10] = f2bf(b2.z); bb.u[11] = f2bf(b2.w);
            bb.u[12] = f2bf(b3.x); bb.u[13] = f2bf(b3.y); bb.u[14] = f2bf(b3.z); bb.u[15] = f2bf(b3.w);
            bu0 = bb.q[0]; bu1 = bb.q[1];
        }
        __syncthreads();  // previous iter's MFMA reads done
        *(uint4*)(asdst) = a0;
        *(uint4*)(asdst + 8) = a1;
        *(uint4*)(bsdst) = bu0;
        *(uint4*)(bsdst + 8) = bu1;
        __syncthreads();

        bf16x8 av[4], bv[4];
        #pragma unroll
        for (int i = 0; i < 4; i++)
            av[i] = *(const bf16x8*)&As[(wm + i * 16 + frow) * LDT + quad * 8];
        #pragma unroll
        for (int i = 0; i < 4; i++)
            bv[i] = *(const bf16x8*)&Bs[(wn + i * 16 + frow) * LDT + quad * 8];
        #pragma unroll
        for (int mt = 0; mt < 4; mt++)
            #pragma unroll
            for (int nt = 0; nt < 4; nt++)
                acc[mt][nt] = __builtin_amdgcn_mfma_f32_16x16x32_bf16(av[mt], bv[nt], acc[mt][nt], 0, 0, 0);

        aptr += BK;
        if (BF16W) bptrb += BK; else bptrf += BK;
    }

    // epilogue: C/D layout col=lane&15, row=quad*4+reg (m89/m91-verified)
    #pragma unroll
    for (int mt = 0; mt < 4; mt++) {
        #pragma unroll
        for (int r = 0; r < 4; r++) {
            int mloc = m0 + wm + mt * 16 + quad * 4 + r;
            if (mloc >= cnt) continue;   // write-guard: no cross-expert H races
            int slot = seg + mloc;
            if (UP) {
                #pragma unroll
                for (int nt = 0; nt < 4; nt++) {
                    int n = n0 + wn + nt * 16 + frow;
                    float v = acc[mt][nt][r];
                    float g = 0.5f * v * (1.0f + erff(v * 0.70710678118654752f)); // exact gelu
                    Hout[(size_t)slot * FDIM + n] = f2bf(g);
                }
            } else {
                int t = rowid[slot];
                float gw = gate[slot];
                #pragma unroll
                for (int nt = 0; nt < 4; nt++) {
                    int n = n0 + wn + nt * 16 + frow;
                    atomicAdd(&out[(size_t)t * DDIM + n], gw * acc[mt][nt][r]);
                }
            }
        }
    }
}

extern "C" void kernel_launch(void* const* d_in, const int* in_sizes, int n_in,
                              void* d_out, int out_size, void* d_ws, size_t ws_size,
                              hipStream_t stream) {
    const float* x  = (const float*)d_in[0];
    const float* Wr = (const float*)d_in[1];
    const float* W1 = (const float*)d_in[2];
    const float* W2 = (const float*)d_in[3];
    float* out = (float*)d_out;

    char* ws = (char*)d_ws;
    size_t off = 0;
    auto alloc = [&](size_t bytes) -> char* {
        char* p = ws + off;
        off = (off + bytes + 255) & ~(size_t)255;
        return p;
    };
    unsigned short* xb   = (unsigned short*)alloc((size_t)N_TOK * DDIM * 2);
    unsigned short* H    = (unsigned short*)alloc((size_t)NSLOT * FDIM * 2);
    int*   rowid   = (int*)alloc(NSLOT * 4);
    float* gatew   = (float*)alloc(NSLOT * 4);
    int*   te      = (int*)alloc(NSLOT * 4);
    float* tw      = (float*)alloc(NSLOT * 4);
    int*   counts  = (int*)alloc(64);
    int*   offsets = (int*)alloc(64);
    int*   cursors = (int*)alloc(64);
    unsigned short* w1b = (unsigned short*)alloc((size_t)NEXP * FDIM * DDIM * 2);
    unsigned short* w2b = (unsigned short*)alloc((size_t)NEXP * DDIM * FDIM * 2);
    const bool bf16w = (off <= ws_size);  // deterministic across calls

    zero_kernel<<<4096, 256, 0, stream>>>(out, counts);
    castN_kernel<<<(N_TOK * DDIM / 4 + 255) / 256, 256, 0, stream>>>(x, xb, N_TOK * DDIM / 4);
    if (bf16w) {
        const int n4 = NEXP * FDIM * DDIM / 4; // 8.39M
        castN_kernel<<<(n4 + 255) / 256, 256, 0, stream>>>(W1, w1b, n4);
        castN_kernel<<<(n4 + 255) / 256, 256, 0, stream>>>(W2, w2b, n4);
    }
    router_kernel<<<N_TOK / 4, 256, 0, stream>>>(x, Wr, te, tw, counts);
    scan_kernel<<<1, 64, 0, stream>>>(counts, offsets, cursors);
    scatter_kernel<<<(N_TOK + 255) / 256, 256, 0, stream>>>(te, tw, offsets, cursors, rowid, gatew);

    if (bf16w) {
        ffn_gemm<DDIM, true,  true ><<<dim3(FDIM / 128, 32, NEXP), 256, 0, stream>>>(xb, W1, w1b, H, out, rowid, gatew, offsets);
        ffn_gemm<FDIM, false, true ><<<dim3(DDIM / 128, 32, NEXP), 256, 0, stream>>>(H,  W2, w2b, H, out, rowid, gatew, offsets);
    } else {
        ffn_gemm<DDIM, true,  false><<<dim3(FDIM / 128, 32, NEXP), 256, 0, stream>>>(xb, W1, w1b, H, out, rowid, gatew, offsets);
        ffn_gemm<FDIM, false, false><<<dim3(DDIM / 128, 32, NEXP), 256, 0, stream>>>(H,  W2, w2b, H, out, rowid, gatew, offsets);
    }
}

// Round 2
// 698.546 us; speedup vs baseline: 1.0478x; 1.0478x over previous
//
#include <hip/hip_runtime.h>
#include <hip/hip_bf16.h>

typedef __attribute__((ext_vector_type(8))) __bf16 bf16x8;
typedef __attribute__((ext_vector_type(4))) float floatx4;

constexpr int N_TOK = 4096;   // B*T
constexpr int DDIM  = 1024;
constexpr int FDIM  = 4096;
constexpr int NEXP  = 8;
constexpr int NSLOT = 2 * N_TOK; // 8192 assignments (top-2)

static __device__ __forceinline__ unsigned short f2bf(float f) {
    union { __hip_bfloat16 h; unsigned short u; } v;
    v.h = __float2bfloat16(f);
    return v.u;
}

// async 16B global->LDS DMA. LDS dest semantics: wave-uniform base + lane*16
// (m104/m108) — we compute per-lane l = base + lane*16 so it matches.
static __device__ __forceinline__ void gl2lds16(const unsigned short* g, unsigned short* l) {
    __builtin_amdgcn_global_load_lds(
        (__attribute__((address_space(1))) void*)g,
        (__attribute__((address_space(3))) void*)l,
        16, 0, 0);
}

// ---------------- x cast (+ counts init) ----------------
__global__ void castX_kernel(const float* __restrict__ src, unsigned short* __restrict__ dst,
                             int* __restrict__ counts) {
    int i = blockIdx.x * 256 + threadIdx.x;
    float4 v = *(const float4*)(src + (size_t)i * 4);
    ushort4 o;
    o.x = f2bf(v.x); o.y = f2bf(v.y); o.z = f2bf(v.z); o.w = f2bf(v.w);
    *(ushort4*)(dst + (size_t)i * 4) = o;
    if (blockIdx.x == 0 && threadIdx.x < NEXP) counts[threadIdx.x] = 0;
}

// ---------------- generic fp32 -> bf16 cast ----------------
__global__ void castN_kernel(const float* __restrict__ src, unsigned short* __restrict__ dst, int n4) {
    int i = blockIdx.x * 256 + threadIdx.x;
    if (i >= n4) return;
    float4 v = *(const float4*)(src + (size_t)i * 4);
    ushort4 o;
    o.x = f2bf(v.x); o.y = f2bf(v.y); o.z = f2bf(v.z); o.w = f2bf(v.w);
    *(ushort4*)(dst + (size_t)i * 4) = o;
}

// ---------------- router: logits -> top2 -> weights ----------------
__global__ void router_kernel(const float* __restrict__ x, const float* __restrict__ Wr,
                              int* __restrict__ te, float* __restrict__ tw,
                              int* __restrict__ counts) {
    __shared__ float wr[NEXP * DDIM]; // 32 KB
    const int tid = threadIdx.x;
    for (int i = tid; i < NEXP * DDIM; i += 256) wr[i] = Wr[i];
    __syncthreads();
    const int wave = tid >> 6, lane = tid & 63;
    const int t = blockIdx.x * 4 + wave;

    float xr[16];
    const float* xp = x + (size_t)t * DDIM;
    #pragma unroll
    for (int i = 0; i < 16; i++) xr[i] = xp[lane + 64 * i];

    float logit[NEXP];
    #pragma unroll
    for (int e = 0; e < NEXP; e++) {
        float s = 0.f;
        #pragma unroll
        for (int i = 0; i < 16; i++) s += xr[i] * wr[e * DDIM + lane + 64 * i];
        #pragma unroll
        for (int off = 32; off > 0; off >>= 1) s += __shfl_xor(s, off, 64);
        logit[e] = s;
    }
    if (lane == 0) {
        int i0 = 0; float l0 = logit[0];
        #pragma unroll
        for (int e = 1; e < NEXP; e++) if (logit[e] > l0) { l0 = logit[e]; i0 = e; }
        int i1 = -1; float l1 = -3.0e38f;
        #pragma unroll
        for (int e = 0; e < NEXP; e++) if (e != i0 && logit[e] > l1) { l1 = logit[e]; i1 = e; }
        // softmax over top-2 logits == renormalized top-2 of full softmax
        float p1 = expf(l1 - l0);
        float w0 = 1.f / (1.f + p1);
        float w1 = p1 * w0;
        te[t * 2] = i0; te[t * 2 + 1] = i1;
        tw[t * 2] = w0; tw[t * 2 + 1] = w1;
        atomicAdd(&counts[i0], 1);
        atomicAdd(&counts[i1], 1);
    }
}

// ---------------- prefix sum over 8 counts ----------------
__global__ void scan_kernel(const int* __restrict__ counts, int* __restrict__ offsets,
                            int* __restrict__ cursors) {
    if (threadIdx.x == 0) {
        int acc = 0;
        for (int e = 0; e < NEXP; e++) { offsets[e] = acc; acc += counts[e]; }
        offsets[NEXP] = acc;
    }
    if (threadIdx.x < NEXP) cursors[threadIdx.x] = 0;
}

// ---------------- scatter tokens into expert buckets ----------------
__global__ void scatter_kernel(const int* __restrict__ te, const float* __restrict__ tw,
                               const int* __restrict__ offsets, int* __restrict__ cursors,
                               int* __restrict__ rowid, float* __restrict__ gate,
                               int* __restrict__ tok2slot) {
    int t = blockIdx.x * 256 + threadIdx.x;
    if (t >= N_TOK) return;
    #pragma unroll
    for (int k = 0; k < 2; k++) {
        int e = te[t * 2 + k];
        int pos = atomicAdd(&cursors[e], 1);
        int slot = offsets[e] + pos;
        rowid[slot] = t;
        gate[slot] = tw[t * 2 + k];
        tok2slot[t * 2 + k] = slot;
    }
}

// ---------------- grouped GEMM, m97-style global_load_lds staging ----------------
// UP:  A = xb gathered rows [cnt x 1024] @ W1^T[1024 x 4096] -> gelu -> H bf16
// DOWN:A = H rows [cnt x 4096] @ W2^T[4096 x 1024] -> gate*  -> Y fp32 per slot
template <int K, bool UP, bool BF16W>
__global__ __launch_bounds__(256)
void ffn_gemm(const unsigned short* __restrict__ A,
              const float* __restrict__ Wf,
              const unsigned short* __restrict__ Wb,
              unsigned short* __restrict__ Hout,
              float* __restrict__ Y,
              const int* __restrict__ rowid,
              const float* __restrict__ gate,
              const int* __restrict__ offsets) {
    constexpr int BM = 128, BN = 128, BK = 32, LDT = 32; // unpadded: required by global_load_lds
    constexpr int NOUT = UP ? FDIM : DDIM;

    const int e = blockIdx.z;
    const int seg = offsets[e];
    const int cnt = offsets[e + 1] - seg;
    const int m0 = blockIdx.y * BM;
    if (m0 >= cnt) return;
    const int n0 = blockIdx.x * BN;

    __shared__ __align__(16) unsigned short As[BM * LDT];
    __shared__ __align__(16) unsigned short Bs[BN * LDT];

    const int tid = threadIdx.x;
    const int lane = tid & 63;
    const int wave = tid >> 6;

    // --- staging coords: wave w stages 32 A rows + 32 B rows (2 DMA instrs each) ---
    const int srow0 = wave * 32 + (lane >> 2);  // + j*16
    const int chunk = lane & 3;                 // 16B chunk within 64B k-row

    const unsigned short* ag[2];
    #pragma unroll
    for (int j = 0; j < 2; j++) {
        int r = srow0 + j * 16;
        int slot = seg + m0 + r;
        if (slot >= NSLOT) slot = NSLOT - 1;    // clamp: stay in valid memory, write-guarded later
        if (UP) { int t = rowid[slot]; ag[j] = A + (size_t)t * DDIM + chunk * 8; }
        else    { ag[j] = A + (size_t)slot * FDIM + chunk * 8; }
    }
    const unsigned short* bg[2];
    #pragma unroll
    for (int j = 0; j < 2; j++) {
        int r = srow0 + j * 16;
        bg[j] = Wb + ((size_t)e * NOUT + n0 + r) * K + chunk * 8;
    }
    unsigned short* asl[2];
    unsigned short* bsl[2];
    #pragma unroll
    for (int j = 0; j < 2; j++) {
        asl[j] = &As[(wave * 32 + j * 16) * LDT] + lane * 8;
        bsl[j] = &Bs[(wave * 32 + j * 16) * LDT] + lane * 8;
    }

    // fallback path (fp32 weights converted in-register)
    const int br = tid >> 1;
    const int bh = (tid & 1) * 16;
    const float* bptrf = Wf + ((size_t)e * NOUT + n0 + br) * K + bh;
    unsigned short* bsdst = &Bs[br * LDT + bh];

    const int wm = (wave >> 1) * 64;
    const int wn = (wave & 1) * 64;
    const int frow = lane & 15;
    const int quad = lane >> 4;

    floatx4 acc[4][4];
    #pragma unroll
    for (int i = 0; i < 4; i++)
        #pragma unroll
        for (int j = 0; j < 4; j++)
            acc[i][j] = (floatx4){0.f, 0.f, 0.f, 0.f};

    for (int k0 = 0; k0 < K; k0 += BK) {
        uint4 bu0, bu1;
        if (!BF16W) {
            float4 b0 = *(const float4*)(bptrf);
            float4 b1 = *(const float4*)(bptrf + 4);
            float4 b2 = *(const float4*)(bptrf + 8);
            float4 b3 = *(const float4*)(bptrf + 12);
            union { unsigned short u[16]; uint4 q[2]; } bb;
            bb.u[0] = f2bf(b0.x); bb.u[1] = f2bf(b0.y); bb.u[2]  = f2bf(b0.z); bb.u[3]  = f2bf(b0.w);
            bb.u[4] = f2bf(b1.x); bb.u[5] = f2bf(b1.y); bb.u[6]  = f2bf(b1.z); bb.u[7]  = f2bf(b1.w);
            bb.u[8] = f2bf(b2.x); bb.u[9] = f2bf(b2.y); bb.u[10] = f2bf(b2.z); bb.u[11] = f2bf(b2.w);
            bb.u[12] = f2bf(b3.x); bb.u[13] = f2bf(b3.y); bb.u[14] = f2bf(b3.z); bb.u[15] = f2bf(b3.w);
            bu0 = bb.q[0]; bu1 = bb.q[1];
            bptrf += BK;
        }
        __syncthreads();                 // WAR: previous iter's ds_reads done
        gl2lds16(ag[0], asl[0]);
        gl2lds16(ag[1], asl[1]);
        if (BF16W) {
            gl2lds16(bg[0], bsl[0]);
            gl2lds16(bg[1], bsl[1]);
            bg[0] += BK; bg[1] += BK;
        } else {
            *(uint4*)(bsdst) = bu0;
            *(uint4*)(bsdst + 8) = bu1;
        }
        ag[0] += BK; ag[1] += BK;
        __syncthreads();                 // drains vmcnt (DMA) + lgkmcnt

        bf16x8 av[4], bv[4];
        #pragma unroll
        for (int i = 0; i < 4; i++)
            av[i] = *(const bf16x8*)&As[(wm + i * 16 + frow) * LDT + quad * 8];
        #pragma unroll
        for (int i = 0; i < 4; i++)
            bv[i] = *(const bf16x8*)&Bs[(wn + i * 16 + frow) * LDT + quad * 8];
        #pragma unroll
        for (int mt = 0; mt < 4; mt++)
            #pragma unroll
            for (int nt = 0; nt < 4; nt++)
                acc[mt][nt] = __builtin_amdgcn_mfma_f32_16x16x32_bf16(av[mt], bv[nt], acc[mt][nt], 0, 0, 0);
    }

    // epilogue: C/D layout col=lane&15, row=quad*4+reg (m89/m91-verified)
    #pragma unroll
    for (int mt = 0; mt < 4; mt++) {
        #pragma unroll
        for (int r = 0; r < 4; r++) {
            int mloc = m0 + wm + mt * 16 + quad * 4 + r;
            if (mloc >= cnt) continue;   // write-guard: no cross-expert races
            int slot = seg + mloc;
            if (UP) {
                #pragma unroll
                for (int nt = 0; nt < 4; nt++) {
                    int n = n0 + wn + nt * 16 + frow;
                    float v = acc[mt][nt][r];
                    float g = 0.5f * v * (1.0f + erff(v * 0.70710678118654752f)); // exact gelu
                    Hout[(size_t)slot * FDIM + n] = f2bf(g);
                }
            } else {
                float gw = gate[slot];
                #pragma unroll
                for (int nt = 0; nt < 4; nt++) {
                    int n = n0 + wn + nt * 16 + frow;
                    Y[(size_t)slot * DDIM + n] = gw * acc[mt][nt][r];
                }
            }
        }
    }
}

// ---------------- combine: out[t] = Y[slot0(t)] + Y[slot1(t)] ----------------
__global__ void combine_kernel(const float* __restrict__ Y, const int* __restrict__ tok2slot,
                               float* __restrict__ out) {
    int idx = blockIdx.x * 256 + threadIdx.x;   // N_TOK*256 threads, 4 floats each
    int t = idx >> 8;
    int c = (idx & 255) * 4;
    int s0 = tok2slot[t * 2], s1 = tok2slot[t * 2 + 1];
    float4 a = *(const float4*)(Y + (size_t)s0 * DDIM + c);
    float4 b = *(const float4*)(Y + (size_t)s1 * DDIM + c);
    *(float4*)(out + (size_t)t * DDIM + c) =
        make_float4(a.x + b.x, a.y + b.y, a.z + b.z, a.w + b.w);
}

extern "C" void kernel_launch(void* const* d_in, const int* in_sizes, int n_in,
                              void* d_out, int out_size, void* d_ws, size_t ws_size,
                              hipStream_t stream) {
    const float* x  = (const float*)d_in[0];
    const float* Wr = (const float*)d_in[1];
    const float* W1 = (const float*)d_in[2];
    const float* W2 = (const float*)d_in[3];
    float* out = (float*)d_out;

    char* ws = (char*)d_ws;
    size_t off = 0;
    auto alloc = [&](size_t bytes) -> char* {
        char* p = ws + off;
        off = (off + bytes + 255) & ~(size_t)255;
        return p;
    };
    unsigned short* xb   = (unsigned short*)alloc((size_t)N_TOK * DDIM * 2);
    unsigned short* H    = (unsigned short*)alloc((size_t)NSLOT * FDIM * 2);
    float* Yb      = (float*)alloc((size_t)NSLOT * DDIM * 4);
    int*   rowid   = (int*)alloc(NSLOT * 4);
    float* gatew   = (float*)alloc(NSLOT * 4);
    int*   te      = (int*)alloc(NSLOT * 4);
    float* tw      = (float*)alloc(NSLOT * 4);
    int*   t2s     = (int*)alloc(NSLOT * 4);
    int*   counts  = (int*)alloc(64);
    int*   offsets = (int*)alloc(64);
    int*   cursors = (int*)alloc(64);
    unsigned short* w1b = (unsigned short*)alloc((size_t)NEXP * FDIM * DDIM * 2);
    unsigned short* w2b = (unsigned short*)alloc((size_t)NEXP * DDIM * FDIM * 2);
    const bool bf16w = (off <= ws_size);  // deterministic across calls

    castX_kernel<<<N_TOK * DDIM / 4 / 256, 256, 0, stream>>>(x, xb, counts);
    if (bf16w) {
        const int n4 = NEXP * FDIM * DDIM / 4; // 8.39M
        castN_kernel<<<(n4 + 255) / 256, 256, 0, stream>>>(W1, w1b, n4);
        castN_kernel<<<(n4 + 255) / 256, 256, 0, stream>>>(W2, w2b, n4);
    }
    router_kernel<<<N_TOK / 4, 256, 0, stream>>>(x, Wr, te, tw, counts);
    scan_kernel<<<1, 64, 0, stream>>>(counts, offsets, cursors);
    scatter_kernel<<<(N_TOK + 255) / 256, 256, 0, stream>>>(te, tw, offsets, cursors, rowid, gatew, t2s);

    if (bf16w) {
        ffn_gemm<DDIM, true,  true ><<<dim3(FDIM / 128, 32, NEXP), 256, 0, stream>>>(xb, W1, w1b, H, Yb, rowid, gatew, offsets);
        ffn_gemm<FDIM, false, true ><<<dim3(DDIM / 128, 32, NEXP), 256, 0, stream>>>(H,  W2, w2b, H, Yb, rowid, gatew, offsets);
    } else {
        ffn_gemm<DDIM, true,  false><<<dim3(FDIM / 128, 32, NEXP), 256, 0, stream>>>(xb, W1, w1b, H, Yb, rowid, gatew, offsets);
        ffn_gemm<FDIM, false, false><<<dim3(DDIM / 128, 32, NEXP), 256, 0, stream>>>(H,  W2, w2b, H, Yb, rowid, gatew, offsets);
    }
    combine_kernel<<<N_TOK, 256, 0, stream>>>(Yb, t2s, out);
}